// Round 6
// baseline (307.425 us; speedup 1.0000x reference)
//
#include <hip/hip_runtime.h>
#include <cmath>
#include <complex>
#include <vector>

#define NN 4096
#define BB 4
#define CCH 8

// ---- workspace float offsets
#define OFF_W3JVAL 0         // 2670 (pad 2688)
#define OFF_W3JOUT 2688      // 10648 -> 13336 (pad 13440)
#define OFF_A      13440     // 24 (pad to 13568)
#define OFF_CTX0   13568     // 4 partials x 4*4096*96 = 6291456 -> ends 6305024 floats
#define CTXS       1572864
// ---- byte offsets (split bf16 u16 regions), all 16B aligned
#define OFFB_KGH   25220096ULL   // u16[4*4096*32]  = 1048576 B
#define OFFB_KGL   26268672ULL
#define OFFB_VGH   27317248ULL   // u16[4*64*96*64] = 3145728 B
#define OFFB_VGL   30462976ULL   // end 33608704

typedef short s16x8 __attribute__((ext_vector_type(8)));
typedef float f32x4 __attribute__((ext_vector_type(4)));
typedef unsigned int u32x4 __attribute__((ext_vector_type(4)));

static __device__ __forceinline__ unsigned short f2bf(float x){
  unsigned u = __float_as_uint(x);
  return (unsigned short)((u + 0x7FFFu + ((u >> 16) & 1u)) >> 16);
}
static __device__ __forceinline__ float bf2f(unsigned short h){
  return __uint_as_float(((unsigned)h) << 16);
}
// cheap split-pack: low16 = trunc-bf16(v), high16 = trunc-bf16(v - hi). 3 VALU ops.
static __device__ __forceinline__ unsigned pk2t(float v){
  unsigned uv = __float_as_uint(v);
  float r = v - __uint_as_float(uv & 0xFFFF0000u);
  return __builtin_amdgcn_perm(__float_as_uint(r), uv, 0x07060302u);
}
// unpack 8 packed u32 -> (high s16x8, low s16x8); h in low16 of each u32
static __device__ __forceinline__ void unpk(u32x4 a, u32x4 b, s16x8& h, s16x8& l){
  u32x4 hw = { __builtin_amdgcn_perm(a[1],a[0],0x05040100u),
               __builtin_amdgcn_perm(a[3],a[2],0x05040100u),
               __builtin_amdgcn_perm(b[1],b[0],0x05040100u),
               __builtin_amdgcn_perm(b[3],b[2],0x05040100u)};
  u32x4 lw = { __builtin_amdgcn_perm(a[1],a[0],0x07060302u),
               __builtin_amdgcn_perm(a[3],a[2],0x07060302u),
               __builtin_amdgcn_perm(b[1],b[0],0x07060302u),
               __builtin_amdgcn_perm(b[3],b[2],0x07060302u)};
  h = __builtin_bit_cast(s16x8, hw);
  l = __builtin_bit_cast(s16x8, lw);
}

// ---------------------------------------------------------------- host: Wigner 3j
namespace {
double dfact(int n){ double r=1.0; for(int i=2;i<=n;++i) r*=(double)i; return r; }

void compute_w3j(int l1,int l2,int l3,double scale,float* dst){
  int d1=2*l1+1,d2=2*l2+1,d3=2*l3+1;
  std::vector<double> Cc((size_t)d1*d2*d3,0.0);
  for(int i=0;i<d1;i++){int m1=i-l1;
   for(int j=0;j<d2;j++){int m2=j-l2;
    for(int k=0;k<d3;k++){int m3=k-l3;
      if(m1+m2!=m3) continue;
      double pref = std::sqrt((2.0*l3+1.0)*dfact(l3+l1-l2)*dfact(l3-l1+l2)*dfact(l1+l2-l3)/dfact(l1+l2+l3+1));
      pref *= std::sqrt(dfact(l3+m3)*dfact(l3-m3)*dfact(l1-m1)*dfact(l1+m1)*dfact(l2-m2)*dfact(l2+m2));
      double s=0.0;
      for(int kk=0;kk<=l1+l2-l3;kk++){
        int dd[6]={kk,l1+l2-l3-kk,l1-m1-kk,l2+m2-kk,l3-l2+m1+kk,l3-l1-m2+kk};
        int mn=dd[0]; for(int t=1;t<6;t++) if(dd[t]<mn) mn=dd[t];
        if(mn<0) continue;
        double prod=1.0; for(int t=0;t<6;t++) prod*=dfact(dd[t]);
        s += ((kk&1)?-1.0:1.0)/prod;
      }
      Cc[((size_t)i*d2+j)*d3+k]=pref*s;
    }}}
  auto qmat=[](int l){
    int d=2*l+1;
    std::vector<std::complex<double>> q((size_t)d*d,std::complex<double>(0,0));
    double rs2=1.0/std::sqrt(2.0);
    for(int m=-l;m<0;m++){
      q[(size_t)(l+m)*d+(l-m)]=std::complex<double>(rs2,0);
      q[(size_t)(l+m)*d+(l+m)]=std::complex<double>(0,-rs2);
    }
    q[(size_t)l*d+l]=std::complex<double>(1,0);
    for(int m=1;m<=l;m++){
      double sg=(m&1)?-1.0:1.0;
      q[(size_t)(l+m)*d+(l+m)]=std::complex<double>(sg*rs2,0);
      q[(size_t)(l+m)*d+(l-m)]=std::complex<double>(0,sg*rs2);
    }
    std::complex<double> f(1,0),mi(0,-1);
    for(int t=0;t<l;t++) f*=mi;
    for(auto&z:q) z*=f;
    return q;
  };
  auto Q1=qmat(l1),Q2=qmat(l2),Q3=qmat(l3);
  std::vector<std::complex<double>> T1((size_t)d1*d2*d3), T2((size_t)d1*d2*d3);
  for(int j=0;j<d1;j++) for(int k=0;k<d2;k++) for(int m=0;m<d3;m++){
    std::complex<double> s(0,0);
    for(int i=0;i<d1;i++) s += Q1[(size_t)i*d1+j]*Cc[((size_t)i*d2+k)*d3+m];
    T1[((size_t)j*d2+k)*d3+m]=s;
  }
  for(int j=0;j<d1;j++) for(int l=0;l<d2;l++) for(int m=0;m<d3;m++){
    std::complex<double> s(0,0);
    for(int k=0;k<d2;k++) s += Q2[(size_t)k*d2+l]*T1[((size_t)j*d2+k)*d3+m];
    T2[((size_t)j*d2+l)*d3+m]=s;
  }
  std::vector<double> Cr((size_t)d1*d2*d3);
  double nrm=0.0;
  for(int j=0;j<d1;j++) for(int l=0;l<d2;l++) for(int n=0;n<d3;n++){
    std::complex<double> s(0,0);
    for(int m=0;m<d3;m++) s += std::conj(Q3[(size_t)m*d3+n])*T2[((size_t)j*d2+l)*d3+m];
    double v=s.real();
    Cr[((size_t)j*d2+l)*d3+n]=v; nrm+=v*v;
  }
  nrm=std::sqrt(nrm);
  double c=scale/nrm;
  for(size_t t=0;t<Cr.size();t++) dst[t]=(float)(Cr[t]*c);
}
} // namespace

// ---------------------------------------------------------------- k_weights
// A[p][i] = sum_w scal[p][w] * bw[val_path(p,i)][w]  (24 floats)
__global__ void k_weights(const float* __restrict__ wli, const float* __restrict__ wval,
                          const float* __restrict__ wout, const float* __restrict__ wlo,
                          float* __restrict__ Aout){
  __shared__ float bws[48];
  __shared__ float scs[64];
  int t = threadIdx.x;
  if(t<48){
    const int val_l1[6]={0,0,1,0,1,1};
    int p=t>>3, w=t&7;
    float s=0.f;
    for(int u=0;u<8;u++) s = fmaf(wli[val_l1[p]*8+u], wval[(p*8+u)*8+w], s);
    bws[t]=s;
  }
  {
    const int out_l1[8]={0,0,1,1,0,0,1,1};
    const int out_l3[8]={0,0,0,0,1,1,1,1};
    int p=t>>3, v=t&7;
    float s=0.f;
    for(int u=0;u<8;u++){
      float a=wli[out_l1[p]*8+u];
      for(int w=0;w<8;w++) s = fmaf(wout[((p*8+u)*8+v)*8+w]*a, wlo[out_l3[p]*8+w], s);
    }
    scs[t]=s*0.35355339059327373f; // 1/sqrt(8)
  }
  __syncthreads();
  if(t<24){
    int p=t/3, i3=t-3*p;
    int vp = (p&1)*3 + i3;
    float s=0.f;
    for(int w=0;w<8;w++) s = fmaf(scs[p*8+w], bws[vp*8+w], s);
    Aout[t]=s;
  }
}

// ---------------------------------------------------------------- k_prep
// grid 256 x 128 thr; block = (64-point-pair panel, half). half0: K rows + even
// out-paths of V; half1: odd out-paths + denom feature + zero pad.
// K: split bf16 rows [idx][32] (cols>=22 zero). V: split bf16 transposed
// [panel][96][64]; features 0..87 g-features (9,13,9,13,...), 88 = e^pb, 89..95 = 0.
__launch_bounds__(128,1)
__global__ void k_prep(const float* __restrict__ feat, const float* __restrict__ sh,
                       const float* __restrict__ log_s, const float* __restrict__ pos_w,
                       const float* __restrict__ pos_b, const float* __restrict__ w3jval,
                       const float* __restrict__ Aw,
                       unsigned short* __restrict__ Kgh, unsigned short* __restrict__ Kgl,
                       unsigned short* __restrict__ Vgh, unsigned short* __restrict__ Vgl){
  __shared__ float Wv[2670];
  __shared__ float As[24];
  int tid = threadIdx.x;
  for(int i=tid;i<2670;i+=128) Wv[i]=w3jval[i];
  if(tid<24) As[tid]=Aw[tid];
  __syncthreads();
  int half = blockIdx.x & 1;
  int idx = (blockIdx.x>>1)*128 + tid;   // 0..16383
  int n = idx & (NN-1);
  const float* fp = feat + (size_t)idx*22;
  const float* shp = sh + n*6;
  float f[22];
  #pragma unroll
  for(int c=0;c<22;c++) f[c]=fp[c];
  float pb = pos_b[0];
  #pragma unroll
  for(int j=0;j<6;j++) pb = fmaf(shp[j], pos_w[j], pb);
  float epb = __expf(pb);
  float y0 = shp[0];
  float y2[5];
  #pragma unroll
  for(int j=0;j<5;j++) y2[j]=shp[1+j];

  unsigned short* vbh = Vgh + (size_t)(idx>>6)*(96*64) + (idx&63);
  unsigned short* vbl = Vgl + (size_t)(idx>>6)*(96*64) + (idx&63);

  if(half==0){
    // ---- K rows (split bf16, RTNE both halves)
    float n4=0.f, n6=0.f;
    #pragma unroll
    for(int c=0;c<9;c++) n4 += f[c]*f[c];
    #pragma unroll
    for(int c=9;c<22;c++) n6 += f[c]*f[c];
    n4 = fmaxf(sqrtf(n4), 1e-12f);
    n6 = fmaxf(sqrtf(n6), 1e-12f);
    float s4 = __expf(log_s[0]), s6 = __expf(log_s[1]);
    float a4 = sqrtf(s4)/n4, a6 = sqrtf(s6)/n6;
    unsigned int* kph = (unsigned int*)(Kgh + (size_t)idx*32);
    unsigned int* kpl = (unsigned int*)(Kgl + (size_t)idx*32);
    float qv[22];
    #pragma unroll
    for(int c=0;c<22;c++) qv[c] = f[c] * (c<9 ? a4 : a6);
    #pragma unroll
    for(int c2=0;c2<11;c2++){
      unsigned h0=f2bf(qv[2*c2]), h1=f2bf(qv[2*c2+1]);
      kph[c2] = h0 | (h1<<16);
      unsigned l0=f2bf(qv[2*c2]-bf2f((unsigned short)h0));
      unsigned l1=f2bf(qv[2*c2+1]-bf2f((unsigned short)h1));
      kpl[c2] = l0 | (l1<<16);
    }
    #pragma unroll
    for(int c2=11;c2<16;c2++){ kph[c2]=0u; kpl[c2]=0u; }
    // ---- even out-paths (l3=4 val paths)
    float t0[9],t1[9],t2[9];
    #pragma unroll
    for(int k=0;k<9;k++){t0[k]=0.f;t1[k]=0.f;t2[k]=0.f;}
    for(int i=0;i<9;i++){ float fi=f[i];
      #pragma unroll
      for(int k=0;k<9;k++) t0[k]=fmaf(fi,Wv[i*9+k],t0[k]); }
    #pragma unroll
    for(int k=0;k<9;k++) t0[k]*=y0;
    for(int i=0;i<9;i++){ float fi=f[i];
      #pragma unroll
      for(int j=0;j<5;j++){ float c_=fi*y2[j];
        #pragma unroll
        for(int k=0;k<9;k++) t1[k]=fmaf(c_,Wv[81+(i*5+j)*9+k],t1[k]); } }
    for(int i=0;i<13;i++){ float fi=f[9+i];
      #pragma unroll
      for(int j=0;j<5;j++){ float c_=fi*y2[j];
        #pragma unroll
        for(int k=0;k<9;k++) t2[k]=fmaf(c_,Wv[486+(i*5+j)*9+k],t2[k]); } }
    const int Ge[4]={0,22,44,66};
    #pragma unroll
    for(int pi=0;pi<4;pi++){
      int p=2*pi;
      float A0=As[p*3], A1=As[p*3+1], A2=As[p*3+2];
      #pragma unroll
      for(int j=0;j<9;j++){
        float v = epb*(A0*t0[j]+A1*t1[j]+A2*t2[j]);
        unsigned short h = f2bf(v);
        size_t o = (size_t)(Ge[pi]+j)*64;
        vbh[o]=h; vbl[o]=f2bf(v - bf2f(h));
      }
    }
  } else {
    // ---- odd out-paths (l3=6 val paths)
    float t3[13],t4[13],t5[13];
    #pragma unroll
    for(int k=0;k<13;k++){t3[k]=0.f;t4[k]=0.f;t5[k]=0.f;}
    for(int i=0;i<9;i++){ float fi=f[i];
      #pragma unroll
      for(int j=0;j<5;j++){ float c_=fi*y2[j];
        #pragma unroll
        for(int k=0;k<13;k++) t3[k]=fmaf(c_,Wv[1071+(i*5+j)*13+k],t3[k]); } }
    for(int i=0;i<13;i++){ float fi=f[9+i];
      #pragma unroll
      for(int k=0;k<13;k++) t4[k]=fmaf(fi,Wv[1656+i*13+k],t4[k]); }
    #pragma unroll
    for(int k=0;k<13;k++) t4[k]*=y0;
    for(int i=0;i<13;i++){ float fi=f[9+i];
      #pragma unroll
      for(int j=0;j<5;j++){ float c_=fi*y2[j];
        #pragma unroll
        for(int k=0;k<13;k++) t5[k]=fmaf(c_,Wv[1825+(i*5+j)*13+k],t5[k]); } }
    const int Go[4]={9,31,53,75};
    #pragma unroll
    for(int pi=0;pi<4;pi++){
      int p=2*pi+1;
      float A0=As[p*3], A1=As[p*3+1], A2=As[p*3+2];
      #pragma unroll
      for(int j=0;j<13;j++){
        float v = epb*(A0*t3[j]+A1*t4[j]+A2*t5[j]);
        unsigned short h = f2bf(v);
        size_t o = (size_t)(Go[pi]+j)*64;
        vbh[o]=h; vbl[o]=f2bf(v - bf2f(h));
      }
    }
    {
      unsigned short h = f2bf(epb);
      vbh[(size_t)88*64]=h; vbl[(size_t)88*64]=f2bf(epb - bf2f(h));
    }
    #pragma unroll
    for(int c=89;c<96;c++){ vbh[(size_t)c*64]=0; vbl[(size_t)c*64]=0; }
  }
}

// ---------------------------------------------------------------- k_attn
// grid 512 = 4b x 4kh x 32qb; block 512 thr (8 waves), BM=128 q rows, KT=64,
// 16 iters, 2 blocks/CU. S computes S^T (A=K, B=Q) so E-writes are b128.
// ctx partial per kh. Split-bf16 3-MFMA products throughout.
#define ESTRIDE 68
__launch_bounds__(512, 4)
__global__ void k_attn(const unsigned short* __restrict__ Kgh,
                       const unsigned short* __restrict__ Kgl,
                       const unsigned short* __restrict__ Vgh,
                       const unsigned short* __restrict__ Vgl,
                       float* __restrict__ ctx0){
  __shared__ __align__(16) unsigned int EsP[128*ESTRIDE];   // 34816 B
  int tid = threadIdx.x;
  int lane = tid & 63, w = tid >> 6;
  int lm = lane & 15, quad = lane >> 4;
  int blk = blockIdx.x;
  int b = blk & 3, kh = (blk>>2)&3, qb = blk >> 4;   // qb 0..31
  int qrow0 = qb * 128;
  const unsigned short* KhB = Kgh + (size_t)b*NN*32;
  const unsigned short* KlB = Kgl + (size_t)b*NN*32;
  const unsigned short* VhB = Vgh + (size_t)b*64*96*64;
  const unsigned short* VlB = Vgl + (size_t)b*64*96*64;
  float* ctx = ctx0 + (size_t)kh*CTXS + (size_t)b*NN*96;

  int sq = w & 3;    // q-tile pair {2sq, 2sq+1} (S and PV)
  int sk = w >> 2;   // S k-tile pair {2sk, 2sk+1}; PV f-group {3sk..3sk+2}

  // Q fragments (B-operand): rows qrow0 + (2sq+q2)*16 + lm
  s16x8 qh[2], ql[2];
  #pragma unroll
  for(int q2=0;q2<2;q2++){
    size_t ro = (size_t)(qrow0 + (2*sq+q2)*16 + lm)*32 + (size_t)quad*8;
    qh[q2] = *(const s16x8*)(KhB + ro);
    ql[q2] = *(const s16x8*)(KlB + ro);
  }
  f32x4 acc[2][3];
  #pragma unroll
  for(int q2=0;q2<2;q2++)
    #pragma unroll
    for(int ft=0;ft<3;ft++)
      #pragma unroll
      for(int i=0;i<4;i++) acc[q2][ft][i]=0.f;

  for(int it=0; it<16; ++it){
    int panel = kh*16 + it;
    int key0 = panel*64;
    // ---- S: A=K, B=Q -> D[m=quad*4+i][q=lm]; exp+pack in regs
    u32x4 pkv[2][2];
    #pragma unroll
    for(int k2=0;k2<2;k2++){
      size_t ko = (size_t)(key0 + (2*sk+k2)*16 + lm)*32 + (size_t)quad*8;
      s16x8 kfh = *(const s16x8*)(KhB + ko);
      s16x8 kfl = *(const s16x8*)(KlB + ko);
      #pragma unroll
      for(int q2=0;q2<2;q2++){
        f32x4 s = {0.f,0.f,0.f,0.f};
        s = __builtin_amdgcn_mfma_f32_16x16x32_bf16(kfl, qh[q2], s, 0,0,0);
        s = __builtin_amdgcn_mfma_f32_16x16x32_bf16(kfh, ql[q2], s, 0,0,0);
        s = __builtin_amdgcn_mfma_f32_16x16x32_bf16(kfh, qh[q2], s, 0,0,0);
        u32x4 pv;
        #pragma unroll
        for(int i=0;i<4;i++) pv[i] = pk2t(__expf(s[i]));
        pkv[k2][q2] = pv;
      }
    }
    __syncthreads();   // prior-iter PV reads of EsP done
    #pragma unroll
    for(int k2=0;k2<2;k2++)
      #pragma unroll
      for(int q2=0;q2<2;q2++)
        *(u32x4*)&EsP[((2*sq+q2)*16 + lm)*ESTRIDE + (2*sk+k2)*16 + quad*4] = pkv[k2][q2];
    __syncthreads();   // EsP visible
    // ---- PV: A=E (row=q), B=V (col=f)
    #pragma unroll
    for(int ks=0; ks<2; ks++){
      s16x8 eh[2], el[2];
      #pragma unroll
      for(int q2=0;q2<2;q2++){
        const u32x4* pp = (const u32x4*)&EsP[((2*sq+q2)*16 + lm)*ESTRIDE + ks*32 + quad*8];
        unpk(pp[0], pp[1], eh[q2], el[q2]);
      }
      #pragma unroll
      for(int ft=0; ft<3; ft++){
        int f = (3*sk + ft)*16 + lm;
        size_t vo = ((size_t)panel*96 + f)*64 + (size_t)ks*32 + quad*8;
        s16x8 vh = *(const s16x8*)(VhB + vo);
        s16x8 vl = *(const s16x8*)(VlB + vo);
        #pragma unroll
        for(int q2=0;q2<2;q2++){
          f32x4 a = acc[q2][ft];
          a = __builtin_amdgcn_mfma_f32_16x16x32_bf16(el[q2], vh, a, 0,0,0);
          a = __builtin_amdgcn_mfma_f32_16x16x32_bf16(eh[q2], vl, a, 0,0,0);
          a = __builtin_amdgcn_mfma_f32_16x16x32_bf16(eh[q2], vh, a, 0,0,0);
          acc[q2][ft] = a;
        }
      }
    }
  }
  // epilogue: D row=q=quad*4+reg, col=f=lm
  #pragma unroll
  for(int q2=0;q2<2;q2++){
    #pragma unroll
    for(int ft=0;ft<3;ft++){
      int col = (3*sk + ft)*16 + lm;
      #pragma unroll
      for(int i=0;i<4;i++){
        int row = qrow0 + (2*sq+q2)*16 + quad*4 + i;
        ctx[(size_t)row*96 + col] = acc[q2][ft][i];
      }
    }
  }
}

// ---------------------------------------------------------------- k_out
// block = 8 points x 32 lanes; g = sum of 4 ctx partials (already sc-contracted)
__launch_bounds__(256, 4)
__global__ void k_out(const float* __restrict__ feat, const float* __restrict__ ctxA,
                      const float* __restrict__ w3jout, float* __restrict__ out){
  __shared__ float Wo[10648];
  __shared__ float g[8][96];
  __shared__ float fs[8][24];
  __shared__ float inv[8];
  int tid = threadIdx.x;
  for(int i=tid;i<10648;i+=256) Wo[i]=w3jout[i];
  int p = tid>>5, l5 = tid&31;
  int idx = blockIdx.x*8 + p;
  const float* cp0 = ctxA + (size_t)idx*96;
  const float* cp1 = cp0 + CTXS;
  const float* cp2 = cp0 + 2*CTXS;
  const float* cp3 = cp0 + 3*CTXS;
  if(l5<22) fs[p][l5] = feat[(size_t)idx*22 + l5];
  if(l5==22) inv[p] = 1.0f / (cp0[88]+cp1[88]+cp2[88]+cp3[88]);
  for(int gi=l5; gi<88; gi+=32)
    g[p][gi] = cp0[gi]+cp1[gi]+cp2[gi]+cp3[gi];
  __syncthreads();
  if(l5 < 22){
    int grp = (l5 < 9) ? 0 : 1;
    int kk  = grp ? (l5-9) : l5;
    int KD  = grp ? 13 : 9;
    float d = 0.f;
    const int IDs[4]={9,9,13,13}, JDs[4]={9,13,9,13}, FBs[4]={0,0,9,9};
    const int WoOff[8]={0,729,1782,2835,4356,5409,6930,8451};
    const int Goff[8]={0,9,22,31,44,53,66,75};
    #pragma unroll
    for(int s4=0;s4<4;s4++){
      const int ID=IDs[s4], JD=JDs[s4], FB=FBs[s4];
      int wb = (grp ? WoOff[s4+4] : WoOff[s4]) + kk;
      int gb = (grp ? Goff[s4+4] : Goff[s4]);
      for(int i=0;i<ID;i++){
        float fi = fs[p][FB+i];
        for(int j=0;j<JD;j++){
          d = fmaf(fi*g[p][gb+j], Wo[wb + (i*JD+j)*KD], d);
        }
      }
    }
    out[(size_t)idx*22 + l5] = d * inv[p];
  }
}

// ---------------------------------------------------------------- launch
extern "C" void kernel_launch(void* const* d_in, const int* in_sizes, int n_in,
                              void* d_out, int out_size, void* d_ws, size_t ws_size,
                              hipStream_t stream){
  (void)in_sizes; (void)n_in; (void)out_size; (void)ws_size;
  static float h_tab[13336];
  {
    const int vpth[6][3]={{4,0,4},{4,2,4},{6,2,4},{4,2,6},{6,0,6},{6,2,6}};
    const int voff[6]={0,81,486,1071,1656,1825};
    for(int p=0;p<6;p++){
      double scl = std::sqrt((2.0*vpth[p][2]+1.0)/(3.0*CCH));
      compute_w3j(vpth[p][0],vpth[p][1],vpth[p][2],scl,h_tab+voff[p]);
    }
    const int opth[8][3]={{4,4,4},{4,6,4},{6,4,4},{6,6,4},{4,4,6},{4,6,6},{6,4,6},{6,6,6}};
    const int ooff[8]={0,729,1782,2835,4356,5409,6930,8451};
    for(int p=0;p<8;p++){
      double scl = std::sqrt((2.0*opth[p][2]+1.0)/(4.0*CCH*CCH));
      compute_w3j(opth[p][0],opth[p][1],opth[p][2],scl,h_tab+2688+ooff[p]);
    }
  }
  float* wsf=(float*)d_ws;
  hipMemcpyAsync(wsf, h_tab, sizeof(h_tab), hipMemcpyHostToDevice, stream);

  const float* feat =(const float*)d_in[0];
  const float* sh   =(const float*)d_in[1];
  const float* log_s=(const float*)d_in[2];
  const float* pos_w=(const float*)d_in[3];
  const float* pos_b=(const float*)d_in[4];
  const float* wli  =(const float*)d_in[5];
  const float* wval =(const float*)d_in[6];
  const float* wout =(const float*)d_in[7];
  const float* wlo  =(const float*)d_in[8];
  float* outp=(float*)d_out;

  unsigned short* Kgh=(unsigned short*)((char*)d_ws + OFFB_KGH);
  unsigned short* Kgl=(unsigned short*)((char*)d_ws + OFFB_KGL);
  unsigned short* Vgh=(unsigned short*)((char*)d_ws + OFFB_VGH);
  unsigned short* Vgl=(unsigned short*)((char*)d_ws + OFFB_VGL);

  hipLaunchKernelGGL(k_weights, dim3(1), dim3(64), 0, stream,
                     wli, wval, wout, wlo, wsf+OFF_A);
  hipLaunchKernelGGL(k_prep, dim3(256), dim3(128), 0, stream,
                     feat, sh, log_s, pos_w, pos_b, wsf+OFF_W3JVAL, wsf+OFF_A,
                     Kgh, Kgl, Vgh, Vgl);
  hipLaunchKernelGGL(k_attn, dim3(512), dim3(512), 0, stream,
                     Kgh, Kgl, Vgh, Vgl, wsf+OFF_CTX0);
  hipLaunchKernelGGL(k_out, dim3(2048), dim3(256), 0, stream,
                     feat, wsf+OFF_CTX0, wsf+OFF_W3JOUT, outp);
}